// Round 5
// baseline (65.442 us; speedup 1.0000x reference)
//
#include <hip/hip_runtime.h>
#include <math.h>

#define NQ     8
#define DIM    256
#define LAYERS 3
#define COUT   8
#define NB     32
#define OH     31
#define OW     31
#define NPATCH (NB*OH*OW)     // 30752
#define PT_BLK 512
#define NTILE  64             // 64 tiles x 8 ch = 512 blocks, XCD-bijective
#define PTOT   (NTILE*PT_BLK) // 32768
#define NPTILE (PTOT/16)      // 2048 16-patch groups
#define NPAIR  72             // packed upper-tri (t,ks) pairs
#define MPACK  (NPAIR*64*8)   // 36864 halves per channel

typedef _Float16 f16x8 __attribute__((ext_vector_type(8)));
typedef _Float16 f16x4 __attribute__((ext_vector_type(4)));
typedef float    f32x4 __attribute__((ext_vector_type(4)));

__device__ __forceinline__ float2 cmul(float2 a, float2 b) {
    return make_float2(a.x*b.x - a.y*b.y, a.x*b.y + a.y*b.x);
}
__device__ __forceinline__ float2 cadd(float2 a, float2 b) {
    return make_float2(a.x + b.x, a.y + b.y);
}

// CNOT-ring permutation (verified round 1)
__device__ __forceinline__ int rho(int i) {
    #pragma unroll
    for (int q = 7; q >= 0; --q) {
        int t = (q + 1) & 7;
        if ((i >> (7 - q)) & 1) i ^= 1 << (7 - t);
    }
    return i;
}

// ---- 1. merged dispatch: blocks [0,2048) build W columns, [2048,4096) extract
__global__ __launch_bounds__(256) void wext(const float* __restrict__ w,
                                            _Float16* __restrict__ At,
                                            _Float16* __restrict__ Bt,
                                            const float* __restrict__ x,
                                            _Float16* __restrict__ sF) {
    __shared__ float2 g[96];
    __shared__ float2 vb[256];
    __shared__ _Float16 sT[16][264];

    if (blockIdx.x < 2048) {
        // ---------------- build_W: col j of U = P K2 P K1 P K0 --------------
        const int j  = blockIdx.x & 255;
        const int ch = blockIdx.x >> 8;
        const int i  = threadIdx.x;
        if (i < 24) {
            const float* wp = w + (ch*24 + i)*3;
            float phi = wp[0], th = wp[1], om = wp[2];
            float cth = cosf(th * 0.5f), sth = sinf(th * 0.5f);
            float a = 0.5f * (phi + om), b = 0.5f * (phi - om);
            float sa, ca, sb, cb;
            sincosf(a, &sa, &ca);
            sincosf(b, &sb, &cb);
            g[i*4+0] = make_float2( cth*ca, -cth*sa);
            g[i*4+1] = make_float2(-sth*cb, -sth*sb);
            g[i*4+2] = make_float2( sth*cb, -sth*sb);
            g[i*4+3] = make_float2( cth*ca,  cth*sa);
        }
        __syncthreads();

        // initial: column j of K0 (Kron element product)
        float2 v = make_float2(1.f, 0.f);
        #pragma unroll
        for (int q = 0; q < 8; ++q) {
            int iq = (i >> (7 - q)) & 1, jq = (j >> (7 - q)) & 1;
            v = cmul(v, g[q*4 + iq*2 + jq]);
        }

        #pragma unroll
        for (int l = 1; l < 3; ++l) {
            // P (cross-thread gather)
            vb[i] = v; __syncthreads();
            v = vb[rho(i)]; __syncthreads();
            // q = 0,1: partner crosses wave boundary -> LDS
            #pragma unroll
            for (int q = 0; q < 2; ++q) {
                int bit = 1 << (7 - q);
                vb[i] = v; __syncthreads();
                float2 y = vb[i ^ bit]; __syncthreads();
                float2 m0 = (i & bit) ? g[(l*8+q)*4+3] : g[(l*8+q)*4+0];
                float2 m1 = (i & bit) ? g[(l*8+q)*4+2] : g[(l*8+q)*4+1];
                v = cadd(cmul(m0, v), cmul(m1, y));
            }
            // q = 2..7: partner within wave -> shfl
            #pragma unroll
            for (int q = 2; q < 8; ++q) {
                int bit = 1 << (7 - q);
                float2 y;
                y.x = __shfl_xor(v.x, bit, 64);
                y.y = __shfl_xor(v.y, bit, 64);
                float2 m0 = (i & bit) ? g[(l*8+q)*4+3] : g[(l*8+q)*4+0];
                float2 m1 = (i & bit) ? g[(l*8+q)*4+2] : g[(l*8+q)*4+1];
                v = cadd(cmul(m0, v), cmul(m1, y));
            }
        }
        // final P, then emit
        vb[i] = v; __syncthreads();
        float2 a = vb[rho(i)];
        float sgn = (i & 128) ? -1.f : 1.f;
        size_t row = ((size_t)ch*256 + j) * 512;
        At[row + i]       = (_Float16)(sgn * a.x);
        At[row + 256 + i] = (_Float16)(sgn * a.y);
        Bt[row + i]       = (_Float16)a.x;
        Bt[row + 256 + i] = (_Float16)a.y;
    } else {
        // ---------------- extract -> fp16 in B-fragment order ---------------
        const int tb  = blockIdx.x - 2048;   // ptile 0..NPTILE-1
        const int tid = threadIdx.x;
        const int wv  = tid >> 6, lane = tid & 63;

        #pragma unroll
        for (int pp = 0; pp < 4; ++pp) {
            int pl = wv*4 + pp;
            int p  = tb*16 + pl;
            float2 v01 = make_float2(0.f,0.f), v23 = make_float2(0.f,0.f);
            if (p < NPATCH) {
                int b = p / (OH*OW); int r = p % (OH*OW);
                int oi = r / OW, oj = r % OW;
                int ci = lane >> 2, fi = lane & 3;
                const float* xb = x + (((size_t)(b*16 + ci))*64 + (oi*2 + fi))*64 + oj*2;
                v01 = *(const float2*)xb;
                v23 = *(const float2*)(xb + 2);
            }
            float ss = v01.x*v01.x + v01.y*v01.y + v23.x*v23.x + v23.y*v23.y;
            #pragma unroll
            for (int m = 1; m < 64; m <<= 1) ss += __shfl_xor(ss, m, 64);
            float inv = ss > 0.f ? 1.f / sqrtf(ss) : 0.f;
            f16x4 o;
            o[0] = (_Float16)(v01.x*inv); o[1] = (_Float16)(v01.y*inv);
            o[2] = (_Float16)(v23.x*inv); o[3] = (_Float16)(v23.y*inv);
            *(f16x4*)&sT[pl][lane*4] = o;
        }
        __syncthreads();

        #pragma unroll
        for (int e = 0; e < 2; ++e) {
            int vi = tid + e*256;            // 0..511
            int ks = vi >> 6, ln = vi & 63;
            int kq = ln >> 4, prow = ln & 15;
            f16x8 o = *(const f16x8*)&sT[prow][ks*32 + kq*8];
            ((f16x8*)sF)[(size_t)tb*512 + vi] = o;
        }
    }
}

// ---- 2. M' = upper-tri-doubled (A^T D A), K=512 fp16 MFMA, packed frag out -
__global__ __launch_bounds__(256) void build_Mp(const _Float16* __restrict__ At,
                                                const _Float16* __restrict__ Bt,
                                                _Float16* __restrict__ Mp) {
    const int ch = blockIdx.z;
    const int ti = blockIdx.y;                       // 0..15
    const int wv = threadIdx.x >> 6;
    const int jt = blockIdx.x * 4 + wv;              // 0..15
    const int jt0 = 2 * (ti >> 1);
    if (jt < jt0) return;
    const int lane = threadIdx.x & 63;
    const int c16 = lane & 15, kq = lane >> 4;
    const int OFFT[16] = {0,8,16,23,30,36,42,47,52,56,60,63,66,68,70,71};
    const int pidx = OFFT[ti] + (jt >> 1) - (ti >> 1);
    _Float16* Mc = Mp + (size_t)ch * MPACK;

    f32x4 acc = {0.f, 0.f, 0.f, 0.f};
    if (jt >= ti) {
        const _Float16* Ar = At + ((size_t)ch*256 + ti*16 + c16) * 512 + kq*8;
        const _Float16* Br = Bt + ((size_t)ch*256 + jt*16 + c16) * 512 + kq*8;
        #pragma unroll
        for (int kk = 0; kk < 16; ++kk) {
            f16x8 af = *(const f16x8*)(Ar + kk*32);
            f16x8 bf = *(const f16x8*)(Br + kk*32);
            acc = __builtin_amdgcn_mfma_f32_16x16x32_f16(af, bf, acc, 0, 0, 0);
        }
    }
    int wsel = (jt & 1) * 16 + c16;
    int kqp = wsel >> 3, jj = wsel & 7;
    #pragma unroll
    for (int reg = 0; reg < 4; ++reg) {
        int i_g = ti*16 + kq*4 + reg;
        int j_g = jt*16 + c16;
        float val = (jt >= ti) ? acc[reg] : 0.f;
        val *= (j_g > i_g) ? 2.f : ((j_g == i_g) ? 1.f : 0.f);
        Mc[(size_t)((pidx*64 + kqp*16 + (kq*4 + reg)) * 8 + jj)] = (_Float16)val;
    }
}

// ---- 3. fused MFMA quadform: out[p,c] = s_p^T M'_c s_p + bias[c] -----------
// 512 blocks XCD-pinned; 8 waves x 64 patches; M' (72KB) in LDS.
__global__ __attribute__((amdgpu_flat_work_group_size(512,512), amdgpu_waves_per_eu(2,2)))
void fusedqf(const _Float16* __restrict__ sF,
             const _Float16* __restrict__ Mp,
             const float* __restrict__ bias,
             float* __restrict__ out) {
    extern __shared__ _Float16 Mlds[];      // 36864 halves = 72 KB
    const int id   = blockIdx.x;
    const int xcd  = id & 7;
    const int g    = id >> 3;
    const int c    = g >> 3;
    const int tile = (g & 7) * 8 + xcd;
    const int tid  = threadIdx.x;
    const int lane = tid & 63;
    const int wv   = tid >> 6;
    const int prow = lane & 15, kq = lane >> 4;
    const int tp0  = tile*32 + wv*4;        // base ptile (of 16 patches)

    // stage M' (linear, coalesced)
    const _Float16* Msrc = Mp + (size_t)c * MPACK;
    #pragma unroll
    for (int it = 0; it < 9; ++it) {
        int vi = it * 512 + tid;
        ((f16x8*)Mlds)[vi] = ((const f16x8*)Msrc)[vi];
    }

    // preload B fragments (coalesced b128 from fragment-order sF)
    f16x8 bfrag[4][8];
    #pragma unroll
    for (int pt = 0; pt < 4; ++pt) {
        const f16x8* src = (const f16x8*)sF + (size_t)(tp0 + pt)*512 + lane;
        #pragma unroll
        for (int ks = 0; ks < 8; ++ks)
            bfrag[pt][ks] = src[ks*64];
    }

    __syncthreads();

    // fold-load base: s[p = tp*16+prow][i = t*16+kq*4 .. +4) at base + t*256 halves
    const _Float16* fold0 = sF + ((size_t)tp0*512 + (kq>>1)*16 + prow)*8 + (kq&1)*4;

    float o0 = 0.f, o1 = 0.f, o2 = 0.f, o3 = 0.f;

    f16x4 svn[4];
    #pragma unroll
    for (int pt = 0; pt < 4; ++pt)
        svn[pt] = *(const f16x4*)(fold0 + pt*4096);

    #pragma unroll
    for (int t = 0; t < 16; ++t) {
        f16x4 svc[4];
        #pragma unroll
        for (int pt = 0; pt < 4; ++pt) svc[pt] = svn[pt];
        if (t < 15) {
            #pragma unroll
            for (int pt = 0; pt < 4; ++pt)
                svn[pt] = *(const f16x4*)(fold0 + pt*4096 + (t+1)*256);
        }

        f32x4 a0 = {0,0,0,0}, a1 = {0,0,0,0}, a2 = {0,0,0,0}, a3 = {0,0,0,0};
        #pragma unroll
        for (int ks = (t >> 1); ks < 8; ++ks) {
            const int OFFT[16] = {0,8,16,23,30,36,42,47,52,56,60,63,66,68,70,71};
            int pidx = OFFT[t] + ks - (t >> 1);          // compile-time constant
            f16x8 a = *(const f16x8*)(Mlds + pidx*512 + lane*8);
            a0 = __builtin_amdgcn_mfma_f32_16x16x32_f16(a, bfrag[0][ks], a0, 0, 0, 0);
            a1 = __builtin_amdgcn_mfma_f32_16x16x32_f16(a, bfrag[1][ks], a1, 0, 0, 0);
            a2 = __builtin_amdgcn_mfma_f32_16x16x32_f16(a, bfrag[2][ks], a2, 0, 0, 0);
            a3 = __builtin_amdgcn_mfma_f32_16x16x32_f16(a, bfrag[3][ks], a3, 0, 0, 0);
        }
        o0 += (float)svc[0][0]*a0[0] + (float)svc[0][1]*a0[1] + (float)svc[0][2]*a0[2] + (float)svc[0][3]*a0[3];
        o1 += (float)svc[1][0]*a1[0] + (float)svc[1][1]*a1[1] + (float)svc[1][2]*a1[2] + (float)svc[1][3]*a1[3];
        o2 += (float)svc[2][0]*a2[0] + (float)svc[2][1]*a2[1] + (float)svc[2][2]*a2[2] + (float)svc[2][3]*a2[3];
        o3 += (float)svc[3][0]*a3[0] + (float)svc[3][1]*a3[1] + (float)svc[3][2]*a3[2] + (float)svc[3][3]*a3[3];
    }

    float ov[4] = {o0, o1, o2, o3};
    float bc = bias[c];
    #pragma unroll
    for (int pt = 0; pt < 4; ++pt) {
        float v = ov[pt];
        v += __shfl_xor(v, 16, 64);
        v += __shfl_xor(v, 32, 64);
        if (kq == 0) {
            int p = (tp0 + pt)*16 + prow;
            if (p < NPATCH) {
                int b = p / (OH*OW); int r2 = p % (OH*OW);
                int oi = r2 / OW, oj = r2 % OW;
                out[(((size_t)(b*COUT + c))*OH + oi)*OW + oj] = v + bc;
            }
        }
    }
}

extern "C" void kernel_launch(void* const* d_in, const int* in_sizes, int n_in,
                              void* d_out, int out_size, void* d_ws, size_t ws_size,
                              hipStream_t stream) {
    const float* x    = (const float*)d_in[0];
    const float* w    = (const float*)d_in[1];
    const float* bias = (const float*)d_in[2];
    float* out = (float*)d_out;

    const size_t OFF_AT  = 0;                       // 8*256*512*2 = 2,097,152
    const size_t OFF_BT  = OFF_AT + 2097152;        // 2,097,152
    const size_t OFF_MP  = OFF_BT + 2097152;        // 8*36864*2 = 589,824
    const size_t OFF_SF  = OFF_MP + 589824;         // 2048*512*16 = 16,777,216
    const size_t TOTAL   = OFF_SF + 16777216;
    if (ws_size < TOTAL) return;

    char* ws = (char*)d_ws;
    _Float16* At = (_Float16*)(ws + OFF_AT);
    _Float16* Bt = (_Float16*)(ws + OFF_BT);
    _Float16* Mp = (_Float16*)(ws + OFF_MP);
    _Float16* sF = (_Float16*)(ws + OFF_SF);

    wext<<<2048 + NPTILE, 256, 0, stream>>>(w, At, Bt, x, sF);
    build_Mp<<<dim3(4, 16, COUT), 256, 0, stream>>>(At, Bt, Mp);
    fusedqf<<<NTILE*COUT, 512, MPACK*sizeof(_Float16), stream>>>(sF, Mp, bias, out);
}